// Round 6
// baseline (87.608 us; speedup 1.0000x reference)
//
#include <hip/hip_runtime.h>

// Problem constants (fixed by reference)
constexpr int B = 4, T = 8, V = 256, F = 64;
constexpr int BT = B * T;            // 32 (b,t) slices
constexpr int CHUNK = 8;             // rows of i per block (proven sweet spot)
constexpr int NCHUNK = V / CHUNK;    // 32 -> grid = 32*32 = 1024 blocks (4 blocks/CU)
constexpr int NXCD = 8;
constexpr int K4 = F / 4;            // 16 float4 chunks per row

typedef float v2f __attribute__((ext_vector_type(2)));

// Block = (bt, 8-row chunk). Thread tid owns column j=tid.
// score(i,j) = sum_f |x_i[f]-x_j[f]|*a[f] is SYMMETRIC, so denom[i]
// (= column-i sum in the reference) equals the row-i sum -> block-local
// reduction, no grid sync / atomics / workspace.
//
// R6: packed-f32 inner loop (v_pk_sub / v_pk_max(neg) / v_pk_fma).
// R7 (REVERTED): transposed col stream — neutral; col loads not the lever.
// R8 (REVERTED): launch_bounds(,8) -> VGPR=32 destroyed the load pipeline.
// R9 (REVERTED): LDS rows + hoisted a/col regs (128 extra VGPR) -> occupancy
//   loss swamped any s_load gain. Confounded experiment.
// R10 (KEPT, neutral): bijective XCD swizzle. Fetch locality not the lever.
// R11 (RERUN — container infra failure last round, no data): the kernel runs
//   in the shadow of the harness's 256MiB poison fill: L2+L3 are fully
//   DIRTY, writeback drains during our dispatch (R8 PMC: WRITE_SIZE=61MB vs
//   8.4MB output), so every miss = dirty-evict + fetch.
//   (a) NT stores: OUT is never re-read -> stream past L2/L3 ('nt'),
//       no write-allocate, no dirty-victim evictions on the store path.
//   (b) rows via LDS broadcast, CLEAN version of R9: SMEM results return
//       out-of-order -> each in-loop s_load use forces lgkmcnt(0) full
//       drain, serializing ~32 line fetches against post-fill latency.
//       Stage the 2KB rowbuf once (128 threads x 1 coalesced float4), read
//       rows as uniform-address ds_read_b128 (broadcast, conflict-free,
//       in-order, pipelineable). af2/col handling UNCHANGED from R0.
__global__ __launch_bounds__(256)
void gl_fused(const float* __restrict__ X, const float* __restrict__ A,
              float* __restrict__ OUT)
{
    const int tid = threadIdx.x;           // column j
    // XCD swizzle: consecutive logical blocks (same bt) pinned to one XCD
    const int lb  = (blockIdx.x & (NXCD - 1)) * (BT * NCHUNK / NXCD)
                  + (blockIdx.x >> 3);
    const int bt  = lb >> 5;               // / NCHUNK
    const int ic  = lb & (NCHUNK - 1);
    const int i0  = ic * CHUNK;

    const float* xbt = X + (size_t)bt * V * F;            // [256][64] tile
    const float4* xrow4 = reinterpret_cast<const float4*>(xbt + (size_t)i0 * F);

    __shared__ float4 rowbuf[CHUNK * K4];  // 2KB: rows i0..i0+7
    __shared__ float wpart[4][CHUNK];      // per-wave partial row sums
    __shared__ float rden[CHUNK];          // reciprocal denominators

    // stage rows: threads 0..127 each load one float4 (coalesced 2KB burst)
    if (tid < CHUNK * K4)
        rowbuf[tid] = xrow4[tid];

    // a -> uniform address, scalarized; keep as packed pairs (as R0)
    v2f af2[F / 2];
#pragma unroll
    for (int k = 0; k < K4; ++k) {
        const float4 v = reinterpret_cast<const float4*>(A)[k];
        af2[2*k+0] = (v2f){v.x, v.y};
        af2[2*k+1] = (v2f){v.z, v.w};
    }

    v2f acc2[CHUNK];
#pragma unroll
    for (int r = 0; r < CHUNK; ++r) acc2[r] = (v2f){0.0f, 0.0f};

    __syncthreads();                       // rowbuf ready

    // stream own column in float4 chunks; CHUNK independent packed fma chains.
    const float4* colp = reinterpret_cast<const float4*>(xbt + (size_t)tid * F);
#pragma unroll
    for (int k = 0; k < K4; ++k) {
        const float4 xv = colp[k];
        const v2f xlo = (v2f){xv.x, xv.y};
        const v2f xhi = (v2f){xv.z, xv.w};
#pragma unroll
        for (int r = 0; r < CHUNK; ++r) {
            const float4 sr = rowbuf[r * K4 + k];       // ds_read_b128 broadcast
            const v2f d0 = xlo - (v2f){sr.x, sr.y};     // v_pk_add (neg mod)
            const v2f d1 = xhi - (v2f){sr.z, sr.w};
            const v2f a0 = __builtin_elementwise_max(d0, -d0);  // v_pk_max (neg mod)
            const v2f a1 = __builtin_elementwise_max(d1, -d1);
            acc2[r] = __builtin_elementwise_fma(a0, af2[2*k+0], acc2[r]); // v_pk_fma
            acc2[r] = __builtin_elementwise_fma(a1, af2[2*k+1], acc2[r]);
        }
    }

    float tmp[CHUNK];
#pragma unroll
    for (int r = 0; r < CHUNK; ++r) {
        const float s = acc2[r].x + acc2[r].y;
        tmp[r] = __expf(fmaxf(s, 0.0f));
    }

    // block reduction: row sum = denominator (symmetry)
    const int lane = tid & 63;
    const int wv   = tid >> 6;
#pragma unroll
    for (int r = 0; r < CHUNK; ++r) {
        float v = tmp[r];
        v += __shfl_xor(v, 32);
        v += __shfl_xor(v, 16);
        v += __shfl_xor(v, 8);
        v += __shfl_xor(v, 4);
        v += __shfl_xor(v, 2);
        v += __shfl_xor(v, 1);
        if (lane == 0) wpart[wv][r] = v;
    }
    __syncthreads();
    if (tid < CHUNK) {
        const float d = wpart[0][tid] + wpart[1][tid] + wpart[2][tid] + wpart[3][tid];
        rden[tid] = 1.0f / d;
    }
    __syncthreads();

    // S[bt, i0+r, tid] = tmp[r] / denom[i0+r]; consecutive tids coalesced.
    // NT: stream past L2/L3 (never re-read; caches are dirty with fill data)
    float* obase = OUT + (((size_t)bt * V + i0) * V) + tid;
#pragma unroll
    for (int r = 0; r < CHUNK; ++r)
        __builtin_nontemporal_store(tmp[r] * rden[r], obase + (size_t)r * V);
}

extern "C" void kernel_launch(void* const* d_in, const int* in_sizes, int n_in,
                              void* d_out, int out_size, void* d_ws, size_t ws_size,
                              hipStream_t stream)
{
    const float* X = (const float*)d_in[0];   // [B,T,V,F] fp32
    const float* A = (const float*)d_in[1];   // [F,1]     fp32
    float* OUT = (float*)d_out;               // [B,T,V,V] fp32

    dim3 grid(BT * NCHUNK), block(256);
    gl_fused<<<grid, block, 0, stream>>>(X, A, OUT);
}